// Round 6
// baseline (455.854 us; speedup 1.0000x reference)
//
#include <hip/hip_runtime.h>
#include <hip/hip_bf16.h>
#include <cstdint>

#define DEVINL __device__ __forceinline__

typedef __attribute__((ext_vector_type(8))) short bf16x8;
typedef __attribute__((ext_vector_type(4))) float f32x4;

DEVINL unsigned short f2bf(float f) {
    union { float f; unsigned u; } v; v.f = f;
    unsigned r = v.u + 0x7fffu + ((v.u >> 16) & 1u);   // RNE
    return (unsigned short)(r >> 16);
}
DEVINL float bf2f(unsigned short h) {
    union { unsigned u; float f; } v; v.u = ((unsigned)h) << 16;
    return v.f;
}

constexpr int BN = 256, BK = 32;
constexpr int PITCH = 40;   // u16/row = 80B; b128 frag reads spread 8-row groups across all 32 banks
constexpr int NSP = 256;    // H*W

// ---------------------------------------------------------------------------
// Transpose + bf16 convert: x[b][2048][256] f32 -> xT[b][256][2048] bf16.
__global__ __launch_bounds__(256)
void xpose(const float* __restrict__ x, unsigned short* __restrict__ xT)
{
    __shared__ float sh[64][65];
    const int b   = blockIdx.y;
    const int kt  = blockIdx.x & 31;     // 2048/64
    const int ntb = blockIdx.x >> 5;     // 256/64
    const int k0 = kt * 64, n0 = ntb * 64;

    const int r = threadIdx.x >> 4;          // 0..15
    const int c = (threadIdx.x & 15) * 4;    // 0..60

    const float* xb = x + ((size_t)b * 2048 + k0) * 256 + n0;
#pragma unroll
    for (int i = 0; i < 4; ++i) {
        float4 v = *(const float4*)(xb + (size_t)(r + 16 * i) * 256 + c);
        sh[r + 16 * i][c + 0] = v.x;
        sh[r + 16 * i][c + 1] = v.y;
        sh[r + 16 * i][c + 2] = v.z;
        sh[r + 16 * i][c + 3] = v.w;
    }
    __syncthreads();
#pragma unroll
    for (int i = 0; i < 4; ++i) {
        const int rr = r + 16 * i;           // n within tile
        ushort4 o;
        o.x = f2bf(sh[c + 0][rr]);
        o.y = f2bf(sh[c + 1][rr]);
        o.z = f2bf(sh[c + 2][rr]);
        o.w = f2bf(sh[c + 3][rr]);
        *(ushort4*)(xT + ((size_t)b * NSP + n0 + rr) * 2048 + k0 + c) = o;
    }
}

// ---------------------------------------------------------------------------
// Y^T[b][n][m] = sigmoid( sum_k W[b][m][k]*XT[b][n][k] + bias[b][m] ), bf16 out.
// BN=256 (full N): W panel fetched once. 512 thr = 8 waves, WM x WN wave grid.
// K-loop: depth-3 reg-staged pipeline, raw s_barrier (NO vmcnt drain), counted
// s_waitcnt vmcnt(N) so next-next tile's global loads stay in flight across
// barriers (T3/T4-lite per m201 recipe). Two named reg sets (no runtime idx).
template<int BM, int WM, int WN>
__global__ __launch_bounds__(512, 2)
void fc_gemm(const float* __restrict__ Wt, const float* __restrict__ bias,
             const unsigned short* __restrict__ X, unsigned short* __restrict__ Yt,
             int M, int K)
{
    constexpr int TM = BM / WM;     // 64
    constexpr int TN = BN / WN;     // 64 or 32
    constexpr int AM = TM / 16;     // 4
    constexpr int AN = TN / 16;     // 4 or 2
    constexpr int AI = BM / 64;     // A-staging float4s per thread (2 or 1)
    constexpr int EPP = BM + 8;     // epilogue LDS pitch (u16)

    const int b  = blockIdx.x;
    const int m0 = blockIdx.y * BM;

    __shared__ __align__(16) unsigned short smem[(2 * BM + 2 * BN) * PITCH];
    unsigned short* sA0 = smem;                       // [2][BM*PITCH]
    unsigned short* sB0 = smem + 2 * BM * PITCH;      // [2][BN*PITCH]

    const int tid  = threadIdx.x;
    const int lane = tid & 63;
    const int wid  = tid >> 6;
    const int wm   = (wid / WN) * TM;
    const int wn   = (wid % WN) * TN;
    const int fr   = lane & 15;
    const int fo   = (lane >> 4) * 8;

    const int am = (AI == 2) ? (tid >> 2) : (tid >> 3);
    const int ac = (AI == 2) ? (tid & 3) * 4 : (tid & 7) * 4;
    const float* Wb = Wt + (size_t)b * M * K + (size_t)m0 * K;

    const int bn = tid >> 1;
    const int bc = (tid & 1) * 16;
    const unsigned short* Xb = X + (size_t)b * NSP * K;

    const int NT = K / BK;          // 64/32/16/8 (even)

    float4 aRa[AI], aRb[AI];        // two named staging sets (tile parity)
    uint4  bRa[2],  bRb[2];

#define LOADA(dst, k0) { _Pragma("unroll") for (int i = 0; i < AI; ++i) \
        dst[i] = *(const float4*)(Wb + (size_t)am * K + (k0) + ac + i * 16); }
#define LOADB(dst, k0) { _Pragma("unroll") for (int i = 0; i < 2; ++i) \
        dst[i] = *(const uint4*)(Xb + (size_t)bn * K + (k0) + bc + i * 8); }
#define STOREA(src, p) { unsigned short* s_ = sA0 + (p) * BM * PITCH; \
        _Pragma("unroll") for (int i = 0; i < AI; ++i) { ushort4 q_; \
            q_.x = f2bf(src[i].x); q_.y = f2bf(src[i].y); \
            q_.z = f2bf(src[i].z); q_.w = f2bf(src[i].w); \
            *(ushort4*)&s_[am * PITCH + ac + i * 16] = q_; } }
#define STOREB(src, p) { unsigned short* s_ = sB0 + (p) * BN * PITCH; \
        _Pragma("unroll") for (int i = 0; i < 2; ++i) \
            *(uint4*)&s_[bn * PITCH + bc + i * 8] = src[i]; }
#define WAITP() { if constexpr (AI == 2) asm volatile("s_waitcnt vmcnt(4)" ::: "memory"); \
                  else                   asm volatile("s_waitcnt vmcnt(3)" ::: "memory"); }
#define WAIT0() { asm volatile("s_waitcnt vmcnt(0)" ::: "memory"); }
#define BARRIER() { asm volatile("s_waitcnt lgkmcnt(0)" ::: "memory"); \
                    __builtin_amdgcn_s_barrier(); \
                    asm volatile("" ::: "memory"); }

    f32x4 acc[AM][AN] = {};

    // Prologue: tiles 0,1 issued; store tile 0 (tile 1 stays in flight).
    LOADA(aRa, 0) LOADB(bRa, 0)
    LOADA(aRb, BK) LOADB(bRb, BK)
    WAITP()
    STOREA(aRa, 0) STOREB(bRa, 0)
    BARRIER()

    // At step s (parity p): read LDS[p]; issue loads tile s+2 -> set p;
    // store set p^1 (tile s+1) -> LDS[p^1]; barrier. vmcnt(AI+2) keeps tile
    // s+2's loads in flight; vmcnt(0) only when no further loads outstanding.
#define KSTEP(p, LA, LB, SA, SB, t_) { \
    const int s_t = (t_); \
    if (s_t + 2 < NT) { LOADA(LA, (s_t + 2) * BK) LOADB(LB, (s_t + 2) * BK) } \
    const unsigned short* a_ = sA0 + (p) * BM * PITCH; \
    const unsigned short* b_ = sB0 + (p) * BN * PITCH; \
    bf16x8 af[AM], bfv[AN]; \
    _Pragma("unroll") for (int i = 0; i < AM; ++i) \
        af[i] = *(const bf16x8*)&a_[(wm + i * 16 + fr) * PITCH + fo]; \
    _Pragma("unroll") for (int i = 0; i < AN; ++i) \
        bfv[i] = *(const bf16x8*)&b_[(wn + i * 16 + fr) * PITCH + fo]; \
    _Pragma("unroll") for (int mi = 0; mi < AM; ++mi) \
        _Pragma("unroll") for (int ni = 0; ni < AN; ++ni) \
            acc[mi][ni] = __builtin_amdgcn_mfma_f32_16x16x32_bf16(af[mi], bfv[ni], acc[mi][ni], 0, 0, 0); \
    if (s_t + 1 < NT) { \
        if (s_t + 2 < NT) WAITP() else WAIT0() \
        STOREA(SA, (p) ^ 1) STOREB(SB, (p) ^ 1) \
    } \
    BARRIER() }

#pragma unroll 1
    for (int t = 0; t < NT; t += 2) {
        KSTEP(0, aRa, bRa, aRb, bRb, t)
        KSTEP(1, aRb, bRb, aRa, bRa, t + 1)
    }
#undef KSTEP
#undef LOADA
#undef LOADB
#undef STOREA
#undef STOREB
#undef WAITP
#undef WAIT0
#undef BARRIER

    // ---- Epilogue: bias+sigmoid+pack, stage [128 n][BM m] in LDS, store full rows.
    const int hi4 = (lane >> 4) * 4;
#pragma unroll 1
    for (int ph = 0; ph < 2; ++ph) {
        if ((wn >> 7) == ph) {
#pragma unroll
            for (int mi = 0; mi < AM; ++mi) {
#pragma unroll
                for (int ni = 0; ni < AN; ++ni) {
                    const int r  = (wn & 127) + ni * 16 + fr;   // n within phase
                    const int mb = wm + mi * 16 + hi4;          // m within block
                    f32x4 v = acc[mi][ni];
                    ushort4 o;
#pragma unroll
                    for (int q = 0; q < 4; ++q) {
                        float yv = v[q] + bias[(size_t)b * M + m0 + mb + q];
                        yv = 1.0f / (1.0f + __expf(-yv));
                        ((unsigned short*)&o)[q] = f2bf(yv);
                    }
                    *(ushort4*)&smem[r * EPP + mb] = o;
                }
            }
        }
        __syncthreads();
        constexpr int TPR = BM / 8;           // threads per row
        constexpr int RPI = 512 / TPR;        // rows per iteration
        const int r = tid / TPR;
        const int c = (tid % TPR) * 8;
#pragma unroll
        for (int it = 0; it < 128 / RPI; ++it) {
            const int rr = r + it * RPI;
            uint4 v = *(const uint4*)&smem[rr * EPP + c];
            *(uint4*)&Yt[((size_t)b * NSP + ph * 128 + rr) * M + m0 + c] = v;
        }
        __syncthreads();
    }
}

// Layer 5: out[b][n] = sum_k act4T[b][n][k] * w5[b][k] + b5[b]   (no sigmoid)
__global__ void fc_final(const unsigned short* __restrict__ A4,
                         const float* __restrict__ W5,
                         const float* __restrict__ B5,
                         float* __restrict__ out)
{
    const int b = blockIdx.x;
    const int t = threadIdx.x;  // 0..255 spatial
    const unsigned short* row = A4 + ((size_t)b * NSP + t) * 128;
    const float* w = W5 + (size_t)b * 128;
    float acc = B5[b];
#pragma unroll
    for (int k = 0; k < 128; k += 8) {
        uint4 v = *(const uint4*)(row + k);
        acc += bf2f((unsigned short)(v.x & 0xffff)) * w[k+0];
        acc += bf2f((unsigned short)(v.x >> 16))    * w[k+1];
        acc += bf2f((unsigned short)(v.y & 0xffff)) * w[k+2];
        acc += bf2f((unsigned short)(v.y >> 16))    * w[k+3];
        acc += bf2f((unsigned short)(v.z & 0xffff)) * w[k+4];
        acc += bf2f((unsigned short)(v.z >> 16))    * w[k+5];
        acc += bf2f((unsigned short)(v.w & 0xffff)) * w[k+6];
        acc += bf2f((unsigned short)(v.w >> 16))    * w[k+7];
    }
    out[b * NSP + t] = acc;
}

extern "C" void kernel_launch(void* const* d_in, const int* in_sizes, int n_in,
                              void* d_out, int out_size, void* d_ws, size_t ws_size,
                              hipStream_t stream)
{
    const float* x  = (const float*)d_in[0];
    const float* w1 = (const float*)d_in[1];
    const float* b1 = (const float*)d_in[2];
    const float* w2 = (const float*)d_in[3];
    const float* b2 = (const float*)d_in[4];
    const float* w3 = (const float*)d_in[5];
    const float* b3 = (const float*)d_in[6];
    const float* w4 = (const float*)d_in[7];
    const float* b4 = (const float*)d_in[8];
    const float* w5 = (const float*)d_in[9];
    const float* b5 = (const float*)d_in[10];

    unsigned short* ws0 = (unsigned short*)d_ws;

    // u16-element offsets. xT dead after L1 -> act2/3/4 reuse its region.
    const size_t XT = (size_t)64 * 256 * 2048;  // 33.55M u16 (67.1 MB)
    unsigned short* xT   = ws0;
    unsigned short* act1 = ws0 + XT;
    unsigned short* act2 = ws0;
    unsigned short* act3 = ws0 + (size_t)64 * 256 * 512;
    unsigned short* act4 = ws0 + (size_t)64 * 256 * (512 + 256);

    xpose<<<dim3(128, 64), dim3(256), 0, stream>>>(x, xT);
    fc_gemm<128, 2, 4><<<dim3(64, 8), dim3(512), 0, stream>>>(w1, b1, xT,   act1, 1024, 2048);
    fc_gemm<128, 2, 4><<<dim3(64, 4), dim3(512), 0, stream>>>(w2, b2, act1, act2,  512, 1024);
    fc_gemm< 64, 1, 8><<<dim3(64, 4), dim3(512), 0, stream>>>(w3, b3, act2, act3,  256,  512);
    fc_gemm< 64, 1, 8><<<dim3(64, 2), dim3(512), 0, stream>>>(w4, b4, act3, act4,  128,  256);
    fc_final<<<dim3(64), dim3(256), 0, stream>>>(act4, w5, b5, (float*)d_out);
}

// Round 7
// 372.780 us; speedup vs baseline: 1.2228x; 1.2228x over previous
//
#include <hip/hip_runtime.h>
#include <hip/hip_bf16.h>
#include <cstdint>

#define DEVINL __device__ __forceinline__

typedef __attribute__((ext_vector_type(8))) short bf16x8;
typedef __attribute__((ext_vector_type(4))) float f32x4;

DEVINL unsigned short f2bf(float f) {
    union { float f; unsigned u; } v; v.f = f;
    unsigned r = v.u + 0x7fffu + ((v.u >> 16) & 1u);   // RNE
    return (unsigned short)(r >> 16);
}
DEVINL float bf2f(unsigned short h) {
    union { unsigned u; float f; } v; v.u = ((unsigned)h) << 16;
    return v.f;
}

constexpr int BM = 64, BN = 256, BK = 32;
constexpr int PA  = 40;    // sA pitch (u16): 80B rows, uniform bank spread
constexpr int NSP = 256;   // H*W

// ---------------------------------------------------------------------------
// Transpose + bf16 convert: x[b][2048][256] f32 -> xT[b][256][2048] bf16.
__global__ __launch_bounds__(256)
void xpose(const float* __restrict__ x, unsigned short* __restrict__ xT)
{
    __shared__ float sh[64][65];
    const int b   = blockIdx.y;
    const int kt  = blockIdx.x & 31;     // 2048/64
    const int ntb = blockIdx.x >> 5;     // 256/64
    const int k0 = kt * 64, n0 = ntb * 64;

    const int r = threadIdx.x >> 4;          // 0..15
    const int c = (threadIdx.x & 15) * 4;    // 0..60

    const float* xb = x + ((size_t)b * 2048 + k0) * 256 + n0;
#pragma unroll
    for (int i = 0; i < 4; ++i) {
        float4 v = *(const float4*)(xb + (size_t)(r + 16 * i) * 256 + c);
        sh[r + 16 * i][c + 0] = v.x;
        sh[r + 16 * i][c + 1] = v.y;
        sh[r + 16 * i][c + 2] = v.z;
        sh[r + 16 * i][c + 3] = v.w;
    }
    __syncthreads();
#pragma unroll
    for (int i = 0; i < 4; ++i) {
        const int rr = r + 16 * i;           // n within tile
        ushort4 o;
        o.x = f2bf(sh[c + 0][rr]);
        o.y = f2bf(sh[c + 1][rr]);
        o.z = f2bf(sh[c + 2][rr]);
        o.w = f2bf(sh[c + 3][rr]);
        *(ushort4*)(xT + ((size_t)b * NSP + n0 + rr) * 2048 + k0 + c) = o;
    }
}

// ---------------------------------------------------------------------------
// Y^T[b][n][m] = sigmoid( sum_k W[b][m][k]*XT[b][n][k] + bias[b][m] ), bf16 out.
// 256 threads = 4 waves, each owning a 64x64 tile of the 64x256 block output.
// BN=256: W panel fetched once. 4 blocks/CU (16 waves, <=128 regs) -> 4
// independent barrier groups hide each other's load/barrier stalls.
// B staged by global_load_lds (linear [256][32] LDS, slot-XOR swizzled via
// pre-swizzled global source); A reg-staged into padded sA (needs f32->bf16).
__global__ __launch_bounds__(256, 4)
void fc_gemm(const float* __restrict__ Wt, const float* __restrict__ bias,
             const unsigned short* __restrict__ X, unsigned short* __restrict__ Yt,
             int M, int K)
{
    const int b  = blockIdx.x;
    const int m0 = blockIdx.y * BM;

    // pool: sA [64][40] u16 (2560) + sB 2 x [256][32] u16 (16384) = 18944 u16.
    // Epilogue reuses pool as [128][72] u16 (9216).
    __shared__ __align__(128) unsigned short pool[64 * PA + 2 * 256 * 32];
    unsigned short* sA = pool;
    unsigned short* sB = pool + 64 * PA;

    const int tid  = threadIdx.x;
    const int lane = tid & 63;
    const int wid  = tid >> 6;            // 0..3
    const int wn   = wid * 64;            // wave's n-offset
    const int fr   = lane & 15;
    const int fo   = (lane >> 4) * 8;

    // A staging: 64x32 f32, thread owns row tid>>2, cols (tid&3)*8 .. +8
    const int am = tid >> 2, ac = (tid & 3) * 8;
    const float* Wb = Wt + (size_t)b * M * K + (size_t)m0 * K + (size_t)am * K + ac;

    // B gload source params: per-lane row/chunk with slot-XOR pre-swizzle
    const int grow = wid * 64 + (lane >> 2);                 // + i*16
    const int gchk = ((lane & 3) ^ ((lane >> 3) & 3)) * 8;   // elem offset in row
    const unsigned short* Xb = X + (size_t)b * NSP * K;

    // B frag read slot (involution of the write swizzle): uniform 8 words/bank
    const int bslot = ((lane >> 4) ^ ((fr >> 1) & 3)) * 8;

    const int NT = K / BK;

    float4 aS[2];

#define LOADA(k0) { aS[0] = *(const float4*)(Wb + (k0)); \
                    aS[1] = *(const float4*)(Wb + (k0) + 4); }
#define STOREA()  { ushort4 p0, p1; \
        p0.x = f2bf(aS[0].x); p0.y = f2bf(aS[0].y); p0.z = f2bf(aS[0].z); p0.w = f2bf(aS[0].w); \
        p1.x = f2bf(aS[1].x); p1.y = f2bf(aS[1].y); p1.z = f2bf(aS[1].z); p1.w = f2bf(aS[1].w); \
        *(ushort4*)&sA[am * PA + ac]     = p0; \
        *(ushort4*)&sA[am * PA + ac + 4] = p1; }
#define GLOADB(k0, bufofs) { \
    _Pragma("unroll") for (int i = 0; i < 4; ++i) { \
        const unsigned short* src_ = Xb + (size_t)(grow + i * 16) * K + (k0) + gchk; \
        const unsigned short* dst_ = sB + (bufofs) + (wid * 64 + i * 16) * 32; \
        __builtin_amdgcn_global_load_lds( \
            (const __attribute__((address_space(1))) void*)src_, \
            (__attribute__((address_space(3))) void*)dst_, 16, 0, 0); } }

    f32x4 acc[4][4] = {};

    // Prologue: tile 0 -> sA + sB[0]; drain (once).
    LOADA(0)
    GLOADB(0, 0)
    STOREA()
    __syncthreads();

#pragma unroll 1
    for (int t = 0; t < NT; ++t) {
        const int pr = (t & 1) * (256 * 32);
        const int pw = ((t + 1) & 1) * (256 * 32);
        if (t + 1 < NT) { LOADA((t + 1) * BK) GLOADB((t + 1) * BK, pw) }

        bf16x8 af[4], bf[4];
#pragma unroll
        for (int i = 0; i < 4; ++i)
            af[i] = *(const bf16x8*)&sA[(i * 16 + fr) * PA + fo];
#pragma unroll
        for (int i = 0; i < 4; ++i)
            bf[i] = *(const bf16x8*)&sB[pr + (wn + i * 16 + fr) * 32 + bslot];

        // bar1: all waves finished reading sA / sB[pr] (reads completed via lgkm0)
        asm volatile("s_waitcnt lgkmcnt(0)" ::: "memory");
        __builtin_amdgcn_s_barrier();

        if (t + 1 < NT) STOREA()   // waits A-loads only (issued before gloads)

#pragma unroll
        for (int mi = 0; mi < 4; ++mi)
#pragma unroll
            for (int ni = 0; ni < 4; ++ni)
                acc[mi][ni] = __builtin_amdgcn_mfma_f32_16x16x32_bf16(af[mi], bf[ni], acc[mi][ni], 0, 0, 0);

        // bar2: full drain (B gloads landed, sA writes visible) = next tile ready
        __syncthreads();
    }
#undef LOADA
#undef STOREA
#undef GLOADB

    // ---- Epilogue: bias+sigmoid+pack, stage [128 n][64 m] in LDS (pitch 72),
    // then store 128B-contiguous rows.
    const int hi4 = (lane >> 4) * 4;
#pragma unroll 1
    for (int ph = 0; ph < 2; ++ph) {
        if ((wn >> 7) == ph) {
#pragma unroll
            for (int mi = 0; mi < 4; ++mi) {
#pragma unroll
                for (int ni = 0; ni < 4; ++ni) {
                    const int r  = (wn & 127) + ni * 16 + fr;   // n within phase
                    const int mb = mi * 16 + hi4;               // m within block
                    f32x4 v = acc[mi][ni];
                    ushort4 o;
#pragma unroll
                    for (int q = 0; q < 4; ++q) {
                        float yv = v[q] + bias[(size_t)b * M + m0 + mb + q];
                        yv = 1.0f / (1.0f + __expf(-yv));
                        ((unsigned short*)&o)[q] = f2bf(yv);
                    }
                    *(ushort4*)&pool[r * 72 + mb] = o;
                }
            }
        }
        __syncthreads();
        const int r = tid >> 3;             // 0..31
        const int c = (tid & 7) * 8;        // 0..56
#pragma unroll
        for (int it = 0; it < 4; ++it) {
            const int rr = r + it * 32;
            uint4 v = *(const uint4*)&pool[rr * 72 + c];
            *(uint4*)&Yt[((size_t)b * NSP + ph * 128 + rr) * M + m0 + c] = v;
        }
        __syncthreads();
    }
}

// Layer 5: out[b][n] = sum_k act4T[b][n][k] * w5[b][k] + b5[b]   (no sigmoid)
__global__ void fc_final(const unsigned short* __restrict__ A4,
                         const float* __restrict__ W5,
                         const float* __restrict__ B5,
                         float* __restrict__ out)
{
    const int b = blockIdx.x;
    const int t = threadIdx.x;  // 0..255 spatial
    const unsigned short* row = A4 + ((size_t)b * NSP + t) * 128;
    const float* w = W5 + (size_t)b * 128;
    float acc = B5[b];
#pragma unroll
    for (int k = 0; k < 128; k += 8) {
        uint4 v = *(const uint4*)(row + k);
        acc += bf2f((unsigned short)(v.x & 0xffff)) * w[k+0];
        acc += bf2f((unsigned short)(v.x >> 16))    * w[k+1];
        acc += bf2f((unsigned short)(v.y & 0xffff)) * w[k+2];
        acc += bf2f((unsigned short)(v.y >> 16))    * w[k+3];
        acc += bf2f((unsigned short)(v.z & 0xffff)) * w[k+4];
        acc += bf2f((unsigned short)(v.z >> 16))    * w[k+5];
        acc += bf2f((unsigned short)(v.w & 0xffff)) * w[k+6];
        acc += bf2f((unsigned short)(v.w >> 16))    * w[k+7];
    }
    out[b * NSP + t] = acc;
}

extern "C" void kernel_launch(void* const* d_in, const int* in_sizes, int n_in,
                              void* d_out, int out_size, void* d_ws, size_t ws_size,
                              hipStream_t stream)
{
    const float* x  = (const float*)d_in[0];
    const float* w1 = (const float*)d_in[1];
    const float* b1 = (const float*)d_in[2];
    const float* w2 = (const float*)d_in[3];
    const float* b2 = (const float*)d_in[4];
    const float* w3 = (const float*)d_in[5];
    const float* b3 = (const float*)d_in[6];
    const float* w4 = (const float*)d_in[7];
    const float* b4 = (const float*)d_in[8];
    const float* w5 = (const float*)d_in[9];
    const float* b5 = (const float*)d_in[10];

    unsigned short* ws0 = (unsigned short*)d_ws;

    // u16-element offsets. xT dead after L1 -> act2/3/4 reuse its region.
    const size_t XT = (size_t)64 * 256 * 2048;  // 33.55M u16 (67.1 MB)
    unsigned short* xT   = ws0;
    unsigned short* act1 = ws0 + XT;
    unsigned short* act2 = ws0;
    unsigned short* act3 = ws0 + (size_t)64 * 256 * 512;
    unsigned short* act4 = ws0 + (size_t)64 * 256 * (512 + 256);

    xpose<<<dim3(128, 64), dim3(256), 0, stream>>>(x, xT);
    fc_gemm<<<dim3(64, 16), dim3(256), 0, stream>>>(w1, b1, xT,   act1, 1024, 2048);
    fc_gemm<<<dim3(64,  8), dim3(256), 0, stream>>>(w2, b2, act1, act2,  512, 1024);
    fc_gemm<<<dim3(64,  4), dim3(256), 0, stream>>>(w3, b3, act2, act3,  256,  512);
    fc_gemm<<<dim3(64,  2), dim3(256), 0, stream>>>(w4, b4, act3, act4,  128,  256);
    fc_final<<<dim3(64), dim3(256), 0, stream>>>(act4, w5, b5, (float*)d_out);
}